// Round 5
// baseline (260.028 us; speedup 1.0000x reference)
//
#include <hip/hip_runtime.h>

// AttnBlock: b=2, c=256, n=4096 (16^3), G=32 groups.
// d_out = [ out0: (2,256,4096) fp32 | attn: (2,4096,4096) fp32 (P^T) ]
// Pipeline (6 kernels):
//   1. prep: conv weights->bf16 (wq,wk nat; wv transposed; wp), GN stats,
//      bias packs (bqkv2=[bq,bk,0], bias2=bp+wp·bv)
//   2. wpv GEMM: wpv = wp·wv (bf16) into Astack rows 512-767
//   3. gn_apply -> hnT[b][n][c] bf16
//   4. merged GEMM M=768: rows 0-511 -> qkT[b][n][512] (transposed store),
//      rows 512-767 -> W2[b][o][m] natural (W2 = (wp·wv)·hn)
//   5. qk_exp: E^T bf16 + column psums (no max-sub; |S|<~10 safe in fp32)
//   6. pv_fused: rsum prologue, stages E^T, writes P^T fp32 (d_out) in-pass,
//      MFMA vs W2, direct out0 = acc*rsum + bias2 + x.
// v4: XCD swizzle on pv_fused (each XCD: one b, both mb, contiguous n-quarter).
// v5 = v4 + (a) nontemporal stores for attn/out0 in pv (write-once data no
//      longer evicts the EbfT/W2 L2 read-set), (b) same XCD swizzle on
//      qk_exp (flat 2048: one b + 16x16 (m,n) quadrant per XCD -> 2 MiB
//      qkT working set L2-resident).

typedef __bf16 bf16_t;
typedef __bf16 bf16x8 __attribute__((ext_vector_type(8)));
typedef float floatx4 __attribute__((ext_vector_type(4)));

typedef __attribute__((address_space(1))) const unsigned int gas_u32;
typedef __attribute__((address_space(3))) unsigned int las_u32;

// async 16B/lane global->LDS. LDS dest is wave-uniform base + lane*16.
__device__ __forceinline__ void gl_lds16(const void* g, void* l) {
  __builtin_amdgcn_global_load_lds((gas_u32*)g, (las_u32*)l, 16, 0, 0);
}

__device__ __forceinline__ unsigned short f2bf(float f) {
  union { float f; unsigned int u; } v; v.f = f;
  return (unsigned short)((v.u + 0x7FFFu + ((v.u >> 16) & 1u)) >> 16);
}
__device__ __forceinline__ float bf2f(unsigned short u) {
  union { unsigned int u; float f; } v; v.u = ((unsigned int)u) << 16;
  return v.f;
}

// ---------------- prep: weight converts + GN stats + bias packs ------------
__global__ void prep_kernel(const float* __restrict__ wq, const float* __restrict__ wk,
                            const float* __restrict__ wv, const float* __restrict__ wp,
                            const float* __restrict__ bq, const float* __restrict__ bk,
                            const float* __restrict__ bv, const float* __restrict__ bp,
                            const float* __restrict__ x, unsigned short* __restrict__ Astack,
                            unsigned short* __restrict__ wpbf, unsigned short* __restrict__ wvT,
                            float* __restrict__ bqkv2, float* __restrict__ bias2,
                            float* __restrict__ mean, float* __restrict__ rstd) {
  __shared__ float T[64 * 67];
  __shared__ float red[256];
  const int blk = blockIdx.x;
  const int tid = threadIdx.x;
  if (blk < 768) {
    int w = blk >> 8;
    const float* src = (w == 0) ? wq : (w == 1) ? wk : wp;
    unsigned short* dst = (w == 0) ? Astack : (w == 1) ? (Astack + 65536) : wpbf;
    int i = (blk & 255) * 256 + tid;
    dst[i] = f2bf(src[i]);
  } else if (blk < 784) {
    int t = blk - 768, tr = t >> 2, tc = t & 3;
#pragma unroll
    for (int rr = 0; rr < 16; ++rr) {
      int r = rr * 4 + (tid >> 6), c = tid & 63;
      T[r * 67 + c] = wv[(size_t)(tr * 64 + r) * 256 + tc * 64 + c];
    }
    __syncthreads();
#pragma unroll
    for (int rr = 0; rr < 16; ++rr) {
      int cc = rr * 4 + (tid >> 6), r = tid & 63;
      wvT[(size_t)(tc * 64 + cc) * 256 + tr * 64 + r] = f2bf(T[r * 67 + cc]);
    }
  } else if (blk < 848) {
    int bg = blk - 784;
    const float* p = x + (size_t)bg * 32768;
    float s = 0.f, ss = 0.f;
    for (int i = tid * 4; i < 32768; i += 1024) {
      float4 v = *(const float4*)&p[i];
      s += v.x + v.y + v.z + v.w;
      ss += v.x * v.x + v.y * v.y + v.z * v.z + v.w * v.w;
    }
    for (int off = 32; off > 0; off >>= 1) {
      s += __shfl_down(s, off);
      ss += __shfl_down(ss, off);
    }
    int wid = tid >> 6;
    if ((tid & 63) == 0) { red[wid] = s; red[64 + wid] = ss; }
    __syncthreads();
    if (tid == 0) {
      float S = red[0] + red[1] + red[2] + red[3];
      float SS = red[64] + red[65] + red[66] + red[67];
      float mu = S * (1.f / 32768.f);
      float var = SS * (1.f / 32768.f) - mu * mu;
      mean[bg] = mu;
      rstd[bg] = rsqrtf(var + 1e-6f);
    }
  } else if (blk == 848) {
    bqkv2[tid] = bq[tid];
    bqkv2[256 + tid] = bk[tid];
    bqkv2[512 + tid] = 0.f;
  } else {
    int bb = blk - 849;  // 0..3
    int o = bb * 64 + (tid >> 2), part = tid & 3;
    float s = 0.f;
#pragma unroll
    for (int j = 0; j < 16; ++j) {
      float4 w4 = *(const float4*)&wp[(size_t)o * 256 + part * 64 + j * 4];
      float4 b4 = *(const float4*)&bv[part * 64 + j * 4];
      s += w4.x * b4.x + w4.y * b4.y + w4.z * b4.z + w4.w * b4.w;
    }
    red[tid] = s;
    __syncthreads();
    if (part == 0) bias2[o] = bp[o] + red[tid] + red[tid + 1] + red[tid + 2] + red[tid + 3];
  }
}

// ---------------- GroupNorm apply + transpose -> hnT[b][n][c] bf16 ---------
__global__ void gn_apply_t_kernel(const float* __restrict__ x, const float* __restrict__ gamma,
                                  const float* __restrict__ beta, const float* __restrict__ mean,
                                  const float* __restrict__ rstd, unsigned short* __restrict__ hnT) {
  int n0 = blockIdx.x * 64, c0 = blockIdx.y * 64, b = blockIdx.z;
  int tid = threadIdx.x;
  __shared__ __align__(16) unsigned short T[64 * 72];
#pragma unroll
  for (int r = 0; r < 4; ++r) {
    int cl = (tid >> 4) + r * 16;
    int nl = (tid & 15) * 4;
    int c = c0 + cl;
    int bg = b * 32 + (c >> 3);
    float mu = mean[bg], rsd = rstd[bg], ga = gamma[c], be = beta[c];
    float4 v = *(const float4*)&x[(size_t)b * 1048576 + (size_t)c * 4096 + n0 + nl];
    ushort4 u;
    u.x = f2bf((v.x - mu) * rsd * ga + be);
    u.y = f2bf((v.y - mu) * rsd * ga + be);
    u.z = f2bf((v.z - mu) * rsd * ga + be);
    u.w = f2bf((v.w - mu) * rsd * ga + be);
    *(ushort4*)&T[cl * 72 + nl] = u;
  }
  __syncthreads();
#pragma unroll
  for (int w = 0; w < 2; ++w) {
    int nl = (tid >> 3) + w * 32;
    int cch = (tid & 7) * 8;
    unsigned short u8[8];
#pragma unroll
    for (int i = 0; i < 8; ++i) u8[i] = T[(cch + i) * 72 + nl];
    size_t o = (size_t)b * 1048576 + (size_t)(n0 + nl) * 256 + c0 + cch;
    *(ushort4*)&hnT[o] = make_ushort4(u8[0], u8[1], u8[2], u8[3]);
    *(ushort4*)&hnT[o + 4] = make_ushort4(u8[4], u8[5], u8[6], u8[7]);
  }
}

// ---------------- Generic TN bf16 MFMA GEMM (bf16 natural store) -----------
// (used once, tiny wpv GEMM -- kept reg-staged)
template <int BM, int BN>
__launch_bounds__(256)
__global__ void gemm_tn(const bf16_t* __restrict__ A, const bf16_t* __restrict__ B, int ldb,
                        unsigned short* __restrict__ C, int N, int K) {
  constexpr int BK = 32, LD = BK + 8;
  constexpr int WM = BM / 2, WN = BN / 2, MI = WM / 16, NI = WN / 16;
  __shared__ __align__(16) bf16_t As[BM * LD];
  __shared__ __align__(16) bf16_t Bs[BN * LD];
  const int tid = threadIdx.x;
  const int lane = tid & 63, wid = tid >> 6;
  const int quad = lane >> 4, l16 = lane & 15;
  const int m0 = blockIdx.y * BM, n0 = blockIdx.x * BN;
  const int wm0 = (wid >> 1) * WM, wn0 = (wid & 1) * WN;

  floatx4 acc[MI][NI];
#pragma unroll
  for (int i = 0; i < MI; ++i)
#pragma unroll
    for (int j = 0; j < NI; ++j) acc[i][j] = (floatx4){0.f, 0.f, 0.f, 0.f};

  const int arow = tid >> 2, akj = (tid & 3) << 3;
  for (int kt = 0; kt < K; kt += BK) {
#pragma unroll
    for (int p = 0; p < BM / 64; ++p) {
      int r = p * 64 + arow;
      *(uint4*)&As[r * LD + akj] = *(const uint4*)&A[(size_t)(m0 + r) * K + kt + akj];
    }
#pragma unroll
    for (int p = 0; p < BN / 64; ++p) {
      int r = p * 64 + arow;
      *(uint4*)&Bs[r * LD + akj] = *(const uint4*)&B[(size_t)(n0 + r) * ldb + kt + akj];
    }
    __syncthreads();
    bf16x8 af[MI], bfr[NI];
#pragma unroll
    for (int i = 0; i < MI; ++i) af[i] = *(const bf16x8*)&As[(wm0 + i * 16 + l16) * LD + quad * 8];
#pragma unroll
    for (int j = 0; j < NI; ++j) bfr[j] = *(const bf16x8*)&Bs[(wn0 + j * 16 + l16) * LD + quad * 8];
#pragma unroll
    for (int i = 0; i < MI; ++i)
#pragma unroll
      for (int j = 0; j < NI; ++j)
        acc[i][j] = __builtin_amdgcn_mfma_f32_16x16x32_bf16(af[i], bfr[j], acc[i][j], 0, 0, 0);
    __syncthreads();
  }

#pragma unroll
  for (int i = 0; i < MI; ++i) {
    int gmb = m0 + wm0 + i * 16 + quad * 4;
#pragma unroll
    for (int j = 0; j < NI; ++j) {
      int gn = n0 + wn0 + j * 16 + l16;
#pragma unroll
      for (int r = 0; r < 4; ++r) C[(size_t)(gmb + r) * N + gn] = f2bf(acc[i][j][r]);
    }
  }
}

// ---------------- merged QKV+W2 GEMM (M=768, K=256) ------------------------
// rows 0-511: transposed store -> qkT[b][n][512] (+bias)
// rows 512-767: natural store -> W2[b][o][4096]
__launch_bounds__(256)
__global__ void gemm_qkvw(const bf16_t* __restrict__ Astack, const bf16_t* __restrict__ hnT,
                          const float* __restrict__ bqkv2, unsigned short* __restrict__ qkT,
                          unsigned short* __restrict__ W2) {
  constexpr int BM = 64, BN = 128, BK = 64, MI = 2, NI = 4;
  __shared__ __align__(16) bf16_t As[BM * BK];
  __shared__ __align__(16) bf16_t Bs[BN * BK];
  const int tid = threadIdx.x;
  const int lane = tid & 63, wid = tid >> 6;
  const int quad = lane >> 4, l16 = lane & 15;
  const int b = blockIdx.z;
  const bf16_t* B = hnT + (size_t)b * 1048576;
  const int m0 = blockIdx.y * BM, n0 = blockIdx.x * BN;
  const int wm0 = (wid >> 1) * 32, wn0 = (wid & 1) * 64;
  const int srow = lane >> 3;                  // row within 8-row chunk
  const int scol = ((lane & 7) ^ srow) << 3;   // swizzled elem offset (16B units)

  floatx4 acc[MI][NI];
#pragma unroll
  for (int i = 0; i < MI; ++i)
#pragma unroll
    for (int j = 0; j < NI; ++j) acc[i][j] = (floatx4){0.f, 0.f, 0.f, 0.f};

  for (int kt = 0; kt < 256; kt += BK) {
#pragma unroll
    for (int p = 0; p < 2; ++p) {
      int rb = wid * 16 + p * 8;
      gl_lds16(&Astack[(size_t)(m0 + rb + srow) * 256 + kt + scol], &As[rb * BK]);
    }
#pragma unroll
    for (int p = 0; p < 4; ++p) {
      int rb = wid * 32 + p * 8;
      gl_lds16(&B[(size_t)(n0 + rb + srow) * 256 + kt + scol], &Bs[rb * BK]);
    }
    __syncthreads();
#pragma unroll
    for (int ks = 0; ks < 2; ++ks) {
      bf16x8 af[MI], bfr[NI];
#pragma unroll
      for (int i = 0; i < MI; ++i) {
        int r = wm0 + i * 16 + l16;
        af[i] = *(const bf16x8*)&As[r * BK + ((((ks << 2) + quad) ^ (r & 7)) << 3)];
      }
#pragma unroll
      for (int j = 0; j < NI; ++j) {
        int r = wn0 + j * 16 + l16;
        bfr[j] = *(const bf16x8*)&Bs[r * BK + ((((ks << 2) + quad) ^ (r & 7)) << 3)];
      }
#pragma unroll
      for (int i = 0; i < MI; ++i)
#pragma unroll
        for (int j = 0; j < NI; ++j)
          acc[i][j] = __builtin_amdgcn_mfma_f32_16x16x32_bf16(af[i], bfr[j], acc[i][j], 0, 0, 0);
    }
    __syncthreads();
  }

#pragma unroll
  for (int i = 0; i < MI; ++i) {
    int gmb = m0 + wm0 + i * 16 + quad * 4;
#pragma unroll
    for (int j = 0; j < NI; ++j) {
      int gn = n0 + wn0 + j * 16 + l16;
      float v[4];
#pragma unroll
      for (int r = 0; r < 4; ++r) v[r] = acc[i][j][r] + bqkv2[gmb + r];
      if (m0 < 512) {  // q/k: transposed bf16 store into qkT[b][n][512]
        ushort4 u = make_ushort4(f2bf(v[0]), f2bf(v[1]), f2bf(v[2]), f2bf(v[3]));
        *(ushort4*)&qkT[(size_t)b * 2097152 + (size_t)gn * 512 + gmb] = u;
      } else {  // W2 rows: natural store [o][n]
#pragma unroll
        for (int r = 0; r < 4; ++r)
          W2[(size_t)b * 1048576 + (size_t)(gmb - 512 + r) * 4096 + gn] = f2bf(v[r]);
      }
    }
  }
}

// ---------------- QK^T + exp + colsum, coalesced E^T store -----------------
// v5: flat grid 2048 with XCD swizzle: xcd k=d&7 -> b=k>>2, quadrant=k&3
//     (m-half, n-half); idx=d>>3 -> 16x16 (m,n) tiles within the quadrant.
//     Working set per XCD: 16 k-panels + 16 q-panels = 2 MiB (L2-resident).
__launch_bounds__(256)
__global__ void gemm_qk_exp(const bf16_t* __restrict__ qkT, unsigned short* __restrict__ EbfT,
                            float* __restrict__ psum) {
  constexpr int BM = 128, BN = 128, BK = 64, MI = 4, NI = 4;
  constexpr int LDC = BM + 8;  // 136
  __shared__ __align__(16) char SMEM[BM * LDC * 2];  // 34816 B; aliases As+Bs (32768 B)
  bf16_t* As = (bf16_t*)SMEM;
  bf16_t* Bs = (bf16_t*)SMEM + BM * BK;
  unsigned short* Ct = (unsigned short*)SMEM;  // [BN][LDC], m-contiguous
  const int tid = threadIdx.x;
  const int lane = tid & 63, wid = tid >> 6;
  const int quad = lane >> 4, l16 = lane & 15;
  const int d = blockIdx.x;
  const int xk = d & 7, idx = d >> 3;
  const int b = xk >> 2, q2 = xk & 3;
  const int mt = ((q2 >> 1) << 4) | (idx >> 4);   // 0..31
  const int nt_ = ((q2 & 1) << 4) | (idx & 15);   // 0..31
  const int m0 = mt * 128, n0 = nt_ * 128;
  const bf16_t* A = qkT + (size_t)b * 2097152 + 256;  // k
  const bf16_t* B = qkT + (size_t)b * 2097152;        // q
  const int wm0 = (wid >> 1) * 64, wn0 = (wid & 1) * 64;
  const int srow = lane >> 3;
  const int scol = ((lane & 7) ^ srow) << 3;

  floatx4 acc[MI][NI];
#pragma unroll
  for (int i = 0; i < MI; ++i)
#pragma unroll
    for (int j = 0; j < NI; ++j) acc[i][j] = (floatx4){0.f, 0.f, 0.f, 0.f};

  for (int kt = 0; kt < 256; kt += BK) {
#pragma unroll
    for (int p = 0; p < 4; ++p) {
      int rb = wid * 32 + p * 8;
      gl_lds16(&A[(size_t)(m0 + rb + srow) * 512 + kt + scol], &As[rb * BK]);
      gl_lds16(&B[(size_t)(n0 + rb + srow) * 512 + kt + scol], &Bs[rb * BK]);
    }
    __syncthreads();
#pragma unroll
    for (int ks = 0; ks < 2; ++ks) {
      bf16x8 af[MI], bfr[NI];
#pragma unroll
      for (int i = 0; i < MI; ++i) {
        int r = wm0 + i * 16 + l16;
        af[i] = *(const bf16x8*)&As[r * BK + ((((ks << 2) + quad) ^ (r & 7)) << 3)];
      }
#pragma unroll
      for (int j = 0; j < NI; ++j) {
        int r = wn0 + j * 16 + l16;
        bfr[j] = *(const bf16x8*)&Bs[r * BK + ((((ks << 2) + quad) ^ (r & 7)) << 3)];
      }
#pragma unroll
      for (int i = 0; i < MI; ++i)
#pragma unroll
        for (int j = 0; j < NI; ++j)
          acc[i][j] = __builtin_amdgcn_mfma_f32_16x16x32_bf16(af[i], bfr[j], acc[i][j], 0, 0, 0);
    }
    __syncthreads();
  }

  float csum[NI] = {0.f, 0.f, 0.f, 0.f};
#pragma unroll
  for (int i = 0; i < MI; ++i) {
    int ml = wm0 + i * 16 + quad * 4;
#pragma unroll
    for (int j = 0; j < NI; ++j) {
      int nl = wn0 + j * 16 + l16;
      float e[4];
#pragma unroll
      for (int r = 0; r < 4; ++r) e[r] = __expf(acc[i][j][r] * 0.0625f);
      csum[j] += (e[0] + e[1]) + (e[2] + e[3]);
      *(ushort4*)&Ct[nl * LDC + ml] = make_ushort4(f2bf(e[0]), f2bf(e[1]), f2bf(e[2]), f2bf(e[3]));
    }
  }
#pragma unroll
  for (int j = 0; j < NI; ++j) {
    csum[j] += __shfl_xor(csum[j], 16);
    csum[j] += __shfl_xor(csum[j], 32);
  }
  if (quad == 0) {
    int my = mt * 2 + (wid >> 1);
#pragma unroll
    for (int j = 0; j < NI; ++j)
      psum[((size_t)b * 64 + my) * 4096 + n0 + wn0 + j * 16 + l16] = csum[j];
  }
  __syncthreads();
#pragma unroll
  for (int pass = 0; pass < 8; ++pass) {
    int row = pass * 16 + (tid >> 4);
    int mc = (tid & 15) * 8;
    uint4 v = *(uint4*)&Ct[row * LDC + mc];
    *(uint4*)&EbfT[(size_t)b * 16777216 + (size_t)(n0 + row) * 4096 + m0 + mc] = v;
  }
}

// ---------------- fused PV GEMM: rsum prologue + P^T write + direct out ----
// flat grid 512, 256 threads. BM=128 (channels), BN=32, K=4096, BK=128.
// v4: XCD swizzle. v5: nontemporal stores for attn + out0 (write-once data;
//     keeps EbfT/W2 read-set resident in the XCD L2).
__launch_bounds__(256)
__global__ void gemm_pv_fused(const bf16_t* __restrict__ W2, const bf16_t* __restrict__ EbfT,
                              const float* __restrict__ psum, const float* __restrict__ bias2,
                              const float* __restrict__ x, float* __restrict__ out0,
                              float* __restrict__ attn) {
  constexpr int BK = 128;
  __shared__ __align__(16) bf16_t As[128 * BK];  // 32768 B
  __shared__ __align__(16) bf16_t Bs[32 * BK];   // 8192 B
  __shared__ float rs[32];
  __shared__ float sred[256];
  const int tid = threadIdx.x;
  const int lane = tid & 63, wid = tid >> 6;
  const int quad = lane >> 4, l16 = lane & 15;
  const int d = blockIdx.x;
  const int xk = d & 7, idx = d >> 3;
  const int b = xk >> 2;
  const int mb = idx >> 5;
  const int n0 = (((xk & 3) << 5) | (idx & 31)) * 32;
  const size_t eb = (size_t)b * 16777216;

  // rsum prologue: 8 threads per n over 64 psum rows
  {
    int nl = tid & 31, rp = tid >> 5;
    float s = 0.f;
#pragma unroll
    for (int i = 0; i < 8; ++i) s += psum[((size_t)b * 64 + rp * 8 + i) * 4096 + n0 + nl];
    sred[tid] = s;
  }
  __syncthreads();
  if (tid < 32) {
    float s = 0.f;
#pragma unroll
    for (int i = 0; i < 8; ++i) s += sred[i * 32 + tid];
    rs[tid] = 1.f / s;
  }
  __syncthreads();

  const int wm0 = (wid >> 1) * 64, wn0 = (wid & 1) * 16;
  const int r4 = lane >> 4, s16 = lane & 15;  // 4 rows x 16 slots per 1KB issue
  const bf16_t* Wb = W2 + (size_t)b * 1048576 + (size_t)(mb * 128) * 4096;
  const bf16_t* Eb = EbfT + eb;
  const int pml = mb * 64 + (tid >> 2);  // attn m-elem within k-tile
  const int pn4 = (tid & 3) * 8;

  floatx4 acc[4];
#pragma unroll
  for (int i = 0; i < 4; ++i) acc[i] = (floatx4){0.f, 0.f, 0.f, 0.f};

  for (int kt = 0; kt < 4096; kt += BK) {
#pragma unroll
    for (int p = 0; p < 8; ++p) {
      int rb = wid * 32 + p * 4;
      int key = ((p & 1) << 2) | r4;  // (row & 7)
      gl_lds16(&Wb[(size_t)(rb + r4) * 4096 + kt + ((s16 ^ key) << 3)], &As[rb * BK]);
    }
#pragma unroll
    for (int p = 0; p < 2; ++p) {
      int rb = wid * 8 + p * 4;
      int key = ((p & 1) << 2) | r4;
      gl_lds16(&Eb[(size_t)(n0 + rb + r4) * 4096 + kt + ((s16 ^ key) << 3)], &Bs[rb * BK]);
    }
    __syncthreads();
    // P^T write: this mb writes 64 of the 128 staged m-rows (nontemporal)
    {
      const unsigned short* Bu = (const unsigned short*)Bs;
      float o[8];
#pragma unroll
      for (int j = 0; j < 8; ++j) {
        int n = pn4 + j;
        o[j] = bf2f(Bu[n * BK + ((((pml >> 3) ^ (n & 7)) << 3) | (pml & 7))]) * rs[n];
      }
      size_t ro = eb + (size_t)(kt + pml) * 4096 + n0 + pn4;
      __builtin_nontemporal_store((floatx4){o[0], o[1], o[2], o[3]}, (floatx4*)&attn[ro]);
      __builtin_nontemporal_store((floatx4){o[4], o[5], o[6], o[7]}, (floatx4*)&attn[ro + 4]);
    }
#pragma unroll
    for (int ks = 0; ks < 4; ++ks) {
      int rn = wn0 + l16;
      bf16x8 bfr = *(const bf16x8*)&Bs[rn * BK + ((((ks << 2) + quad) ^ (rn & 7)) << 3)];
#pragma unroll
      for (int i = 0; i < 4; ++i) {
        int rm = wm0 + i * 16 + l16;
        bf16x8 af = *(const bf16x8*)&As[rm * BK + ((((ks << 2) + quad) ^ (rm & 7)) << 3)];
        acc[i] = __builtin_amdgcn_mfma_f32_16x16x32_bf16(af, bfr, acc[i], 0, 0, 0);
      }
    }
    __syncthreads();
  }

  const float* xb = x + (size_t)b * 1048576;
  float* ob = out0 + (size_t)b * 1048576;
  int gn = n0 + wn0 + l16;
  float cs = rs[wn0 + l16];
#pragma unroll
  for (int i = 0; i < 4; ++i) {
    int o = mb * 128 + wm0 + i * 16 + quad * 4;
#pragma unroll
    for (int r = 0; r < 4; ++r)
      __builtin_nontemporal_store(
          acc[i][r] * cs + bias2[o + r] + xb[(size_t)(o + r) * 4096 + gn],
          &ob[(size_t)(o + r) * 4096 + gn]);
  }
}

extern "C" void kernel_launch(void* const* d_in, const int* in_sizes, int n_in,
                              void* d_out, int out_size, void* d_ws, size_t ws_size,
                              hipStream_t stream) {
  const float* x = (const float*)d_in[0];
  const float* gamma = (const float*)d_in[1];
  const float* beta = (const float*)d_in[2];
  const float* wq = (const float*)d_in[3];
  const float* bq = (const float*)d_in[4];
  const float* wk = (const float*)d_in[5];
  const float* bk = (const float*)d_in[6];
  const float* wv = (const float*)d_in[7];
  const float* bv = (const float*)d_in[8];
  const float* wp = (const float*)d_in[9];
  const float* bp = (const float*)d_in[10];

  float* out0 = (float*)d_out;            // (2,256,4096)
  float* attn = (float*)d_out + 2097152;  // (2,4096,4096) = P^T fp32

  char* ws = (char*)d_ws;
  unsigned short* Astack = (unsigned short*)(ws + 0);      // 768x256 bf16 = 393216 B
  unsigned short* wpbf = (unsigned short*)(ws + 393216);   // 256x256 bf16
  unsigned short* wvT = (unsigned short*)(ws + 524288);    // 256x256 bf16
  float* bqkv2 = (float*)(ws + 655360);                    // 768
  float* bias2 = (float*)(ws + 658432);                    // 256
  float* gmean = (float*)(ws + 659456);                    // 64
  float* grstd = (float*)(ws + 659712);                    // 64
  float* psum = (float*)(ws + 1048576);                    // (2,64,4096) fp32
  unsigned short* hnT = (unsigned short*)(ws + 4194304);   // (2,4096,256) bf16
  unsigned short* qkT = (unsigned short*)(ws + 8388608);   // (2,4096,512) bf16
  unsigned short* W2 = (unsigned short*)(ws + 16777216);   // (2,256,4096) bf16
  unsigned short* EbfT = (unsigned short*)(ws + 20971520); // (2,4096,4096) bf16

  prep_kernel<<<853, 256, 0, stream>>>(wq, wk, wv, wp, bq, bk, bv, bp, x, Astack, wpbf, wvT,
                                       bqkv2, bias2, gmean, grstd);

  // wpv = wp·wv -> Astack rows 512-767 (A=wp_bf [o][c'], B=wvT [c''][c'])
  gemm_tn<64, 128><<<dim3(2, 4, 1), 256, 0, stream>>>((const bf16_t*)wpbf, (const bf16_t*)wvT, 256,
                                                      Astack + 131072, 256, 256);

  gn_apply_t_kernel<<<dim3(64, 4, 2), 256, 0, stream>>>(x, gamma, beta, gmean, grstd, hnT);

  // merged QKV + W2 GEMM
  gemm_qkvw<<<dim3(32, 12, 2), 256, 0, stream>>>((const bf16_t*)Astack, (const bf16_t*)hnT, bqkv2,
                                                 qkT, W2);

  gemm_qk_exp<<<2048, 256, 0, stream>>>((const bf16_t*)qkT, EbfT, psum);

  gemm_pv_fused<<<512, 256, 0, stream>>>((const bf16_t*)W2, (const bf16_t*)EbfT, psum,
                                         bias2, x, out0, attn);
}

// Round 6
// 253.802 us; speedup vs baseline: 1.0245x; 1.0245x over previous
//
#include <hip/hip_runtime.h>

// AttnBlock: b=2, c=256, n=4096 (16^3), G=32 groups.
// d_out = [ out0: (2,256,4096) fp32 | attn: (2,4096,4096) fp32 (P^T) ]
// Pipeline (6 kernels):
//   1. prep: conv weights->bf16 (wq,wk nat; wv transposed; wp), GN stats,
//      bias packs (bqkv2=[bq,bk,0], bias2=bp+wp·bv)
//   2. wpv GEMM: wpv = wp·wv (bf16) into Astack rows 512-767
//   3. gn_apply -> hnT[b][n][c] bf16
//   4. merged GEMM M=768: rows 0-511 -> qkT[b][n][512] (transposed store),
//      rows 512-767 -> W2[b][o][m] natural (W2 = (wp·wv)·hn)
//   5. qk_exp: E^T bf16 + column psums (no max-sub; |S|<~10 safe in fp32)
//   6. pv_fused: rsum prologue, stages E^T, writes P^T fp32 (d_out) in-pass,
//      MFMA vs W2, direct out0 = acc*rsum + bias2 + x.
// v4: XCD swizzle on pv_fused (each XCD: one b, both mb, contiguous n-quarter).
// v6 = v4 + XCD swizzle on qk_exp ONLY (v5's nontemporal stores REVERTED:
//      nt stores complete at HBM not L2, so pv's per-iteration __syncthreads
//      vmcnt(0) drain waited ~4x longer on the in-loop attn stores).

typedef __bf16 bf16_t;
typedef __bf16 bf16x8 __attribute__((ext_vector_type(8)));
typedef float floatx4 __attribute__((ext_vector_type(4)));

typedef __attribute__((address_space(1))) const unsigned int gas_u32;
typedef __attribute__((address_space(3))) unsigned int las_u32;

// async 16B/lane global->LDS. LDS dest is wave-uniform base + lane*16.
__device__ __forceinline__ void gl_lds16(const void* g, void* l) {
  __builtin_amdgcn_global_load_lds((gas_u32*)g, (las_u32*)l, 16, 0, 0);
}

__device__ __forceinline__ unsigned short f2bf(float f) {
  union { float f; unsigned int u; } v; v.f = f;
  return (unsigned short)((v.u + 0x7FFFu + ((v.u >> 16) & 1u)) >> 16);
}
__device__ __forceinline__ float bf2f(unsigned short u) {
  union { unsigned int u; float f; } v; v.u = ((unsigned int)u) << 16;
  return v.f;
}

// ---------------- prep: weight converts + GN stats + bias packs ------------
__global__ void prep_kernel(const float* __restrict__ wq, const float* __restrict__ wk,
                            const float* __restrict__ wv, const float* __restrict__ wp,
                            const float* __restrict__ bq, const float* __restrict__ bk,
                            const float* __restrict__ bv, const float* __restrict__ bp,
                            const float* __restrict__ x, unsigned short* __restrict__ Astack,
                            unsigned short* __restrict__ wpbf, unsigned short* __restrict__ wvT,
                            float* __restrict__ bqkv2, float* __restrict__ bias2,
                            float* __restrict__ mean, float* __restrict__ rstd) {
  __shared__ float T[64 * 67];
  __shared__ float red[256];
  const int blk = blockIdx.x;
  const int tid = threadIdx.x;
  if (blk < 768) {
    int w = blk >> 8;
    const float* src = (w == 0) ? wq : (w == 1) ? wk : wp;
    unsigned short* dst = (w == 0) ? Astack : (w == 1) ? (Astack + 65536) : wpbf;
    int i = (blk & 255) * 256 + tid;
    dst[i] = f2bf(src[i]);
  } else if (blk < 784) {
    int t = blk - 768, tr = t >> 2, tc = t & 3;
#pragma unroll
    for (int rr = 0; rr < 16; ++rr) {
      int r = rr * 4 + (tid >> 6), c = tid & 63;
      T[r * 67 + c] = wv[(size_t)(tr * 64 + r) * 256 + tc * 64 + c];
    }
    __syncthreads();
#pragma unroll
    for (int rr = 0; rr < 16; ++rr) {
      int cc = rr * 4 + (tid >> 6), r = tid & 63;
      wvT[(size_t)(tc * 64 + cc) * 256 + tr * 64 + r] = f2bf(T[r * 67 + cc]);
    }
  } else if (blk < 848) {
    int bg = blk - 784;
    const float* p = x + (size_t)bg * 32768;
    float s = 0.f, ss = 0.f;
    for (int i = tid * 4; i < 32768; i += 1024) {
      float4 v = *(const float4*)&p[i];
      s += v.x + v.y + v.z + v.w;
      ss += v.x * v.x + v.y * v.y + v.z * v.z + v.w * v.w;
    }
    for (int off = 32; off > 0; off >>= 1) {
      s += __shfl_down(s, off);
      ss += __shfl_down(ss, off);
    }
    int wid = tid >> 6;
    if ((tid & 63) == 0) { red[wid] = s; red[64 + wid] = ss; }
    __syncthreads();
    if (tid == 0) {
      float S = red[0] + red[1] + red[2] + red[3];
      float SS = red[64] + red[65] + red[66] + red[67];
      float mu = S * (1.f / 32768.f);
      float var = SS * (1.f / 32768.f) - mu * mu;
      mean[bg] = mu;
      rstd[bg] = rsqrtf(var + 1e-6f);
    }
  } else if (blk == 848) {
    bqkv2[tid] = bq[tid];
    bqkv2[256 + tid] = bk[tid];
    bqkv2[512 + tid] = 0.f;
  } else {
    int bb = blk - 849;  // 0..3
    int o = bb * 64 + (tid >> 2), part = tid & 3;
    float s = 0.f;
#pragma unroll
    for (int j = 0; j < 16; ++j) {
      float4 w4 = *(const float4*)&wp[(size_t)o * 256 + part * 64 + j * 4];
      float4 b4 = *(const float4*)&bv[part * 64 + j * 4];
      s += w4.x * b4.x + w4.y * b4.y + w4.z * b4.z + w4.w * b4.w;
    }
    red[tid] = s;
    __syncthreads();
    if (part == 0) bias2[o] = bp[o] + red[tid] + red[tid + 1] + red[tid + 2] + red[tid + 3];
  }
}

// ---------------- GroupNorm apply + transpose -> hnT[b][n][c] bf16 ---------
__global__ void gn_apply_t_kernel(const float* __restrict__ x, const float* __restrict__ gamma,
                                  const float* __restrict__ beta, const float* __restrict__ mean,
                                  const float* __restrict__ rstd, unsigned short* __restrict__ hnT) {
  int n0 = blockIdx.x * 64, c0 = blockIdx.y * 64, b = blockIdx.z;
  int tid = threadIdx.x;
  __shared__ __align__(16) unsigned short T[64 * 72];
#pragma unroll
  for (int r = 0; r < 4; ++r) {
    int cl = (tid >> 4) + r * 16;
    int nl = (tid & 15) * 4;
    int c = c0 + cl;
    int bg = b * 32 + (c >> 3);
    float mu = mean[bg], rsd = rstd[bg], ga = gamma[c], be = beta[c];
    float4 v = *(const float4*)&x[(size_t)b * 1048576 + (size_t)c * 4096 + n0 + nl];
    ushort4 u;
    u.x = f2bf((v.x - mu) * rsd * ga + be);
    u.y = f2bf((v.y - mu) * rsd * ga + be);
    u.z = f2bf((v.z - mu) * rsd * ga + be);
    u.w = f2bf((v.w - mu) * rsd * ga + be);
    *(ushort4*)&T[cl * 72 + nl] = u;
  }
  __syncthreads();
#pragma unroll
  for (int w = 0; w < 2; ++w) {
    int nl = (tid >> 3) + w * 32;
    int cch = (tid & 7) * 8;
    unsigned short u8[8];
#pragma unroll
    for (int i = 0; i < 8; ++i) u8[i] = T[(cch + i) * 72 + nl];
    size_t o = (size_t)b * 1048576 + (size_t)(n0 + nl) * 256 + c0 + cch;
    *(ushort4*)&hnT[o] = make_ushort4(u8[0], u8[1], u8[2], u8[3]);
    *(ushort4*)&hnT[o + 4] = make_ushort4(u8[4], u8[5], u8[6], u8[7]);
  }
}

// ---------------- Generic TN bf16 MFMA GEMM (bf16 natural store) -----------
// (used once, tiny wpv GEMM -- kept reg-staged)
template <int BM, int BN>
__launch_bounds__(256)
__global__ void gemm_tn(const bf16_t* __restrict__ A, const bf16_t* __restrict__ B, int ldb,
                        unsigned short* __restrict__ C, int N, int K) {
  constexpr int BK = 32, LD = BK + 8;
  constexpr int WM = BM / 2, WN = BN / 2, MI = WM / 16, NI = WN / 16;
  __shared__ __align__(16) bf16_t As[BM * LD];
  __shared__ __align__(16) bf16_t Bs[BN * LD];
  const int tid = threadIdx.x;
  const int lane = tid & 63, wid = tid >> 6;
  const int quad = lane >> 4, l16 = lane & 15;
  const int m0 = blockIdx.y * BM, n0 = blockIdx.x * BN;
  const int wm0 = (wid >> 1) * WM, wn0 = (wid & 1) * WN;

  floatx4 acc[MI][NI];
#pragma unroll
  for (int i = 0; i < MI; ++i)
#pragma unroll
    for (int j = 0; j < NI; ++j) acc[i][j] = (floatx4){0.f, 0.f, 0.f, 0.f};

  const int arow = tid >> 2, akj = (tid & 3) << 3;
  for (int kt = 0; kt < K; kt += BK) {
#pragma unroll
    for (int p = 0; p < BM / 64; ++p) {
      int r = p * 64 + arow;
      *(uint4*)&As[r * LD + akj] = *(const uint4*)&A[(size_t)(m0 + r) * K + kt + akj];
    }
#pragma unroll
    for (int p = 0; p < BN / 64; ++p) {
      int r = p * 64 + arow;
      *(uint4*)&Bs[r * LD + akj] = *(const uint4*)&B[(size_t)(n0 + r) * ldb + kt + akj];
    }
    __syncthreads();
    bf16x8 af[MI], bfr[NI];
#pragma unroll
    for (int i = 0; i < MI; ++i) af[i] = *(const bf16x8*)&As[(wm0 + i * 16 + l16) * LD + quad * 8];
#pragma unroll
    for (int j = 0; j < NI; ++j) bfr[j] = *(const bf16x8*)&Bs[(wn0 + j * 16 + l16) * LD + quad * 8];
#pragma unroll
    for (int i = 0; i < MI; ++i)
#pragma unroll
      for (int j = 0; j < NI; ++j)
        acc[i][j] = __builtin_amdgcn_mfma_f32_16x16x32_bf16(af[i], bfr[j], acc[i][j], 0, 0, 0);
    __syncthreads();
  }

#pragma unroll
  for (int i = 0; i < MI; ++i) {
    int gmb = m0 + wm0 + i * 16 + quad * 4;
#pragma unroll
    for (int j = 0; j < NI; ++j) {
      int gn = n0 + wn0 + j * 16 + l16;
#pragma unroll
      for (int r = 0; r < 4; ++r) C[(size_t)(gmb + r) * N + gn] = f2bf(acc[i][j][r]);
    }
  }
}

// ---------------- merged QKV+W2 GEMM (M=768, K=256) ------------------------
// rows 0-511: transposed store -> qkT[b][n][512] (+bias)
// rows 512-767: natural store -> W2[b][o][4096]
__launch_bounds__(256)
__global__ void gemm_qkvw(const bf16_t* __restrict__ Astack, const bf16_t* __restrict__ hnT,
                          const float* __restrict__ bqkv2, unsigned short* __restrict__ qkT,
                          unsigned short* __restrict__ W2) {
  constexpr int BM = 64, BN = 128, BK = 64, MI = 2, NI = 4;
  __shared__ __align__(16) bf16_t As[BM * BK];
  __shared__ __align__(16) bf16_t Bs[BN * BK];
  const int tid = threadIdx.x;
  const int lane = tid & 63, wid = tid >> 6;
  const int quad = lane >> 4, l16 = lane & 15;
  const int b = blockIdx.z;
  const bf16_t* B = hnT + (size_t)b * 1048576;
  const int m0 = blockIdx.y * BM, n0 = blockIdx.x * BN;
  const int wm0 = (wid >> 1) * 32, wn0 = (wid & 1) * 64;
  const int srow = lane >> 3;                  // row within 8-row chunk
  const int scol = ((lane & 7) ^ srow) << 3;   // swizzled elem offset (16B units)

  floatx4 acc[MI][NI];
#pragma unroll
  for (int i = 0; i < MI; ++i)
#pragma unroll
    for (int j = 0; j < NI; ++j) acc[i][j] = (floatx4){0.f, 0.f, 0.f, 0.f};

  for (int kt = 0; kt < 256; kt += BK) {
#pragma unroll
    for (int p = 0; p < 2; ++p) {
      int rb = wid * 16 + p * 8;
      gl_lds16(&Astack[(size_t)(m0 + rb + srow) * 256 + kt + scol], &As[rb * BK]);
    }
#pragma unroll
    for (int p = 0; p < 4; ++p) {
      int rb = wid * 32 + p * 8;
      gl_lds16(&B[(size_t)(n0 + rb + srow) * 256 + kt + scol], &Bs[rb * BK]);
    }
    __syncthreads();
#pragma unroll
    for (int ks = 0; ks < 2; ++ks) {
      bf16x8 af[MI], bfr[NI];
#pragma unroll
      for (int i = 0; i < MI; ++i) {
        int r = wm0 + i * 16 + l16;
        af[i] = *(const bf16x8*)&As[r * BK + ((((ks << 2) + quad) ^ (r & 7)) << 3)];
      }
#pragma unroll
      for (int j = 0; j < NI; ++j) {
        int r = wn0 + j * 16 + l16;
        bfr[j] = *(const bf16x8*)&Bs[r * BK + ((((ks << 2) + quad) ^ (r & 7)) << 3)];
      }
#pragma unroll
      for (int i = 0; i < MI; ++i)
#pragma unroll
        for (int j = 0; j < NI; ++j)
          acc[i][j] = __builtin_amdgcn_mfma_f32_16x16x32_bf16(af[i], bfr[j], acc[i][j], 0, 0, 0);
    }
    __syncthreads();
  }

#pragma unroll
  for (int i = 0; i < MI; ++i) {
    int gmb = m0 + wm0 + i * 16 + quad * 4;
#pragma unroll
    for (int j = 0; j < NI; ++j) {
      int gn = n0 + wn0 + j * 16 + l16;
      float v[4];
#pragma unroll
      for (int r = 0; r < 4; ++r) v[r] = acc[i][j][r] + bqkv2[gmb + r];
      if (m0 < 512) {  // q/k: transposed bf16 store into qkT[b][n][512]
        ushort4 u = make_ushort4(f2bf(v[0]), f2bf(v[1]), f2bf(v[2]), f2bf(v[3]));
        *(ushort4*)&qkT[(size_t)b * 2097152 + (size_t)gn * 512 + gmb] = u;
      } else {  // W2 rows: natural store [o][n]
#pragma unroll
        for (int r = 0; r < 4; ++r)
          W2[(size_t)b * 1048576 + (size_t)(gmb - 512 + r) * 4096 + gn] = f2bf(v[r]);
      }
    }
  }
}

// ---------------- QK^T + exp + colsum, coalesced E^T store -----------------
// v6: flat grid 2048 with XCD swizzle: xcd k=d&7 -> b=k>>2, quadrant=k&3
//     (m-half, n-half); idx=d>>3 -> 16x16 (m,n) tiles within the quadrant.
//     Working set per XCD: 16 k-panels + 16 q-panels = 2 MiB (L2-resident).
__launch_bounds__(256)
__global__ void gemm_qk_exp(const bf16_t* __restrict__ qkT, unsigned short* __restrict__ EbfT,
                            float* __restrict__ psum) {
  constexpr int BM = 128, BN = 128, BK = 64, MI = 4, NI = 4;
  constexpr int LDC = BM + 8;  // 136
  __shared__ __align__(16) char SMEM[BM * LDC * 2];  // 34816 B; aliases As+Bs (32768 B)
  bf16_t* As = (bf16_t*)SMEM;
  bf16_t* Bs = (bf16_t*)SMEM + BM * BK;
  unsigned short* Ct = (unsigned short*)SMEM;  // [BN][LDC], m-contiguous
  const int tid = threadIdx.x;
  const int lane = tid & 63, wid = tid >> 6;
  const int quad = lane >> 4, l16 = lane & 15;
  const int d = blockIdx.x;
  const int xk = d & 7, idx = d >> 3;
  const int b = xk >> 2, q2 = xk & 3;
  const int mt = ((q2 >> 1) << 4) | (idx >> 4);   // 0..31
  const int nt_ = ((q2 & 1) << 4) | (idx & 15);   // 0..31
  const int m0 = mt * 128, n0 = nt_ * 128;
  const bf16_t* A = qkT + (size_t)b * 2097152 + 256;  // k
  const bf16_t* B = qkT + (size_t)b * 2097152;        // q
  const int wm0 = (wid >> 1) * 64, wn0 = (wid & 1) * 64;
  const int srow = lane >> 3;
  const int scol = ((lane & 7) ^ srow) << 3;

  floatx4 acc[MI][NI];
#pragma unroll
  for (int i = 0; i < MI; ++i)
#pragma unroll
    for (int j = 0; j < NI; ++j) acc[i][j] = (floatx4){0.f, 0.f, 0.f, 0.f};

  for (int kt = 0; kt < 256; kt += BK) {
#pragma unroll
    for (int p = 0; p < 4; ++p) {
      int rb = wid * 32 + p * 8;
      gl_lds16(&A[(size_t)(m0 + rb + srow) * 512 + kt + scol], &As[rb * BK]);
      gl_lds16(&B[(size_t)(n0 + rb + srow) * 512 + kt + scol], &Bs[rb * BK]);
    }
    __syncthreads();
#pragma unroll
    for (int ks = 0; ks < 2; ++ks) {
      bf16x8 af[MI], bfr[NI];
#pragma unroll
      for (int i = 0; i < MI; ++i) {
        int r = wm0 + i * 16 + l16;
        af[i] = *(const bf16x8*)&As[r * BK + ((((ks << 2) + quad) ^ (r & 7)) << 3)];
      }
#pragma unroll
      for (int j = 0; j < NI; ++j) {
        int r = wn0 + j * 16 + l16;
        bfr[j] = *(const bf16x8*)&Bs[r * BK + ((((ks << 2) + quad) ^ (r & 7)) << 3)];
      }
#pragma unroll
      for (int i = 0; i < MI; ++i)
#pragma unroll
        for (int j = 0; j < NI; ++j)
          acc[i][j] = __builtin_amdgcn_mfma_f32_16x16x32_bf16(af[i], bfr[j], acc[i][j], 0, 0, 0);
    }
    __syncthreads();
  }

  float csum[NI] = {0.f, 0.f, 0.f, 0.f};
#pragma unroll
  for (int i = 0; i < MI; ++i) {
    int ml = wm0 + i * 16 + quad * 4;
#pragma unroll
    for (int j = 0; j < NI; ++j) {
      int nl = wn0 + j * 16 + l16;
      float e[4];
#pragma unroll
      for (int r = 0; r < 4; ++r) e[r] = __expf(acc[i][j][r] * 0.0625f);
      csum[j] += (e[0] + e[1]) + (e[2] + e[3]);
      *(ushort4*)&Ct[nl * LDC + ml] = make_ushort4(f2bf(e[0]), f2bf(e[1]), f2bf(e[2]), f2bf(e[3]));
    }
  }
#pragma unroll
  for (int j = 0; j < NI; ++j) {
    csum[j] += __shfl_xor(csum[j], 16);
    csum[j] += __shfl_xor(csum[j], 32);
  }
  if (quad == 0) {
    int my = mt * 2 + (wid >> 1);
#pragma unroll
    for (int j = 0; j < NI; ++j)
      psum[((size_t)b * 64 + my) * 4096 + n0 + wn0 + j * 16 + l16] = csum[j];
  }
  __syncthreads();
#pragma unroll
  for (int pass = 0; pass < 8; ++pass) {
    int row = pass * 16 + (tid >> 4);
    int mc = (tid & 15) * 8;
    uint4 v = *(uint4*)&Ct[row * LDC + mc];
    *(uint4*)&EbfT[(size_t)b * 16777216 + (size_t)(n0 + row) * 4096 + m0 + mc] = v;
  }
}

// ---------------- fused PV GEMM: rsum prologue + P^T write + direct out ----
// flat grid 512, 256 threads. BM=128 (channels), BN=32, K=4096, BK=128.
// v4: XCD swizzle. v6: plain stores (nt reverted).
__launch_bounds__(256)
__global__ void gemm_pv_fused(const bf16_t* __restrict__ W2, const bf16_t* __restrict__ EbfT,
                              const float* __restrict__ psum, const float* __restrict__ bias2,
                              const float* __restrict__ x, float* __restrict__ out0,
                              float* __restrict__ attn) {
  constexpr int BK = 128;
  __shared__ __align__(16) bf16_t As[128 * BK];  // 32768 B
  __shared__ __align__(16) bf16_t Bs[32 * BK];   // 8192 B
  __shared__ float rs[32];
  __shared__ float sred[256];
  const int tid = threadIdx.x;
  const int lane = tid & 63, wid = tid >> 6;
  const int quad = lane >> 4, l16 = lane & 15;
  const int d = blockIdx.x;
  const int xk = d & 7, idx = d >> 3;
  const int b = xk >> 2;
  const int mb = idx >> 5;
  const int n0 = (((xk & 3) << 5) | (idx & 31)) * 32;
  const size_t eb = (size_t)b * 16777216;

  // rsum prologue: 8 threads per n over 64 psum rows
  {
    int nl = tid & 31, rp = tid >> 5;
    float s = 0.f;
#pragma unroll
    for (int i = 0; i < 8; ++i) s += psum[((size_t)b * 64 + rp * 8 + i) * 4096 + n0 + nl];
    sred[tid] = s;
  }
  __syncthreads();
  if (tid < 32) {
    float s = 0.f;
#pragma unroll
    for (int i = 0; i < 8; ++i) s += sred[i * 32 + tid];
    rs[tid] = 1.f / s;
  }
  __syncthreads();

  const int wm0 = (wid >> 1) * 64, wn0 = (wid & 1) * 16;
  const int r4 = lane >> 4, s16 = lane & 15;  // 4 rows x 16 slots per 1KB issue
  const bf16_t* Wb = W2 + (size_t)b * 1048576 + (size_t)(mb * 128) * 4096;
  const bf16_t* Eb = EbfT + eb;
  const int pml = mb * 64 + (tid >> 2);  // attn m-elem within k-tile
  const int pn4 = (tid & 3) * 8;

  floatx4 acc[4];
#pragma unroll
  for (int i = 0; i < 4; ++i) acc[i] = (floatx4){0.f, 0.f, 0.f, 0.f};

  for (int kt = 0; kt < 4096; kt += BK) {
#pragma unroll
    for (int p = 0; p < 8; ++p) {
      int rb = wid * 32 + p * 4;
      int key = ((p & 1) << 2) | r4;  // (row & 7)
      gl_lds16(&Wb[(size_t)(rb + r4) * 4096 + kt + ((s16 ^ key) << 3)], &As[rb * BK]);
    }
#pragma unroll
    for (int p = 0; p < 2; ++p) {
      int rb = wid * 8 + p * 4;
      int key = ((p & 1) << 2) | r4;
      gl_lds16(&Eb[(size_t)(n0 + rb + r4) * 4096 + kt + ((s16 ^ key) << 3)], &Bs[rb * BK]);
    }
    __syncthreads();
    // P^T write: this mb writes 64 of the 128 staged m-rows
    {
      const unsigned short* Bu = (const unsigned short*)Bs;
      float o[8];
#pragma unroll
      for (int j = 0; j < 8; ++j) {
        int n = pn4 + j;
        o[j] = bf2f(Bu[n * BK + ((((pml >> 3) ^ (n & 7)) << 3) | (pml & 7))]) * rs[n];
      }
      size_t ro = eb + (size_t)(kt + pml) * 4096 + n0 + pn4;
      *(float4*)&attn[ro] = make_float4(o[0], o[1], o[2], o[3]);
      *(float4*)&attn[ro + 4] = make_float4(o[4], o[5], o[6], o[7]);
    }
#pragma unroll
    for (int ks = 0; ks < 4; ++ks) {
      int rn = wn0 + l16;
      bf16x8 bfr = *(const bf16x8*)&Bs[rn * BK + ((((ks << 2) + quad) ^ (rn & 7)) << 3)];
#pragma unroll
      for (int i = 0; i < 4; ++i) {
        int rm = wm0 + i * 16 + l16;
        bf16x8 af = *(const bf16x8*)&As[rm * BK + ((((ks << 2) + quad) ^ (rm & 7)) << 3)];
        acc[i] = __builtin_amdgcn_mfma_f32_16x16x32_bf16(af, bfr, acc[i], 0, 0, 0);
      }
    }
    __syncthreads();
  }

  const float* xb = x + (size_t)b * 1048576;
  float* ob = out0 + (size_t)b * 1048576;
  int gn = n0 + wn0 + l16;
  float cs = rs[wn0 + l16];
#pragma unroll
  for (int i = 0; i < 4; ++i) {
    int o = mb * 128 + wm0 + i * 16 + quad * 4;
#pragma unroll
    for (int r = 0; r < 4; ++r)
      ob[(size_t)(o + r) * 4096 + gn] =
          acc[i][r] * cs + bias2[o + r] + xb[(size_t)(o + r) * 4096 + gn];
  }
}

extern "C" void kernel_launch(void* const* d_in, const int* in_sizes, int n_in,
                              void* d_out, int out_size, void* d_ws, size_t ws_size,
                              hipStream_t stream) {
  const float* x = (const float*)d_in[0];
  const float* gamma = (const float*)d_in[1];
  const float* beta = (const float*)d_in[2];
  const float* wq = (const float*)d_in[3];
  const float* bq = (const float*)d_in[4];
  const float* wk = (const float*)d_in[5];
  const float* bk = (const float*)d_in[6];
  const float* wv = (const float*)d_in[7];
  const float* bv = (const float*)d_in[8];
  const float* wp = (const float*)d_in[9];
  const float* bp = (const float*)d_in[10];

  float* out0 = (float*)d_out;            // (2,256,4096)
  float* attn = (float*)d_out + 2097152;  // (2,4096,4096) = P^T fp32

  char* ws = (char*)d_ws;
  unsigned short* Astack = (unsigned short*)(ws + 0);      // 768x256 bf16 = 393216 B
  unsigned short* wpbf = (unsigned short*)(ws + 393216);   // 256x256 bf16
  unsigned short* wvT = (unsigned short*)(ws + 524288);    // 256x256 bf16
  float* bqkv2 = (float*)(ws + 655360);                    // 768
  float* bias2 = (float*)(ws + 658432);                    // 256
  float* gmean = (float*)(ws + 659456);                    // 64
  float* grstd = (float*)(ws + 659712);                    // 64
  float* psum = (float*)(ws + 1048576);                    // (2,64,4096) fp32
  unsigned short* hnT = (unsigned short*)(ws + 4194304);   // (2,4096,256) bf16
  unsigned short* qkT = (unsigned short*)(ws + 8388608);   // (2,4096,512) bf16
  unsigned short* W2 = (unsigned short*)(ws + 16777216);   // (2,256,4096) bf16
  unsigned short* EbfT = (unsigned short*)(ws + 20971520); // (2,4096,4096) bf16

  prep_kernel<<<853, 256, 0, stream>>>(wq, wk, wv, wp, bq, bk, bv, bp, x, Astack, wpbf, wvT,
                                       bqkv2, bias2, gmean, grstd);

  // wpv = wp·wv -> Astack rows 512-767 (A=wp_bf [o][c'], B=wvT [c''][c'])
  gemm_tn<64, 128><<<dim3(2, 4, 1), 256, 0, stream>>>((const bf16_t*)wpbf, (const bf16_t*)wvT, 256,
                                                      Astack + 131072, 256, 256);

  gn_apply_t_kernel<<<dim3(64, 4, 2), 256, 0, stream>>>(x, gamma, beta, gmean, grstd, hnT);

  // merged QKV + W2 GEMM
  gemm_qkvw<<<dim3(32, 12, 2), 256, 0, stream>>>((const bf16_t*)Astack, (const bf16_t*)hnT, bqkv2,
                                                 qkT, W2);

  gemm_qk_exp<<<2048, 256, 0, stream>>>((const bf16_t*)qkT, EbfT, psum);

  gemm_pv_fused<<<512, 256, 0, stream>>>((const bf16_t*)W2, (const bf16_t*)EbfT, psum,
                                         bias2, x, out0, attn);
}